// Round 8
// baseline (2722.125 us; speedup 1.0000x reference)
//
#include <hip/hip_runtime.h>
#include <hip/hip_bf16.h>
#include <math.h>

#define DEV __device__ __forceinline__

typedef __attribute__((ext_vector_type(8))) short short8;
typedef __attribute__((ext_vector_type(4))) float f32x4;
typedef __attribute__((ext_vector_type(4))) unsigned int u32x4;

static constexpr int Bsz  = 1024;
static constexpr int T    = 100;
static constexpr int TM1  = 99;
static constexpr int H    = 512;
static constexpr int OUTD = 64;
static constexpr int H2   = 1024;
static constexpr int BT   = Bsz * T;        // 102400

DEV unsigned short f2bf(float f){
  unsigned int u = __float_as_uint(f);
  u += 0x7fffu + ((u >> 16) & 1u);          // round-to-nearest-even
  return (unsigned short)(u >> 16);
}
DEV unsigned pack2(float lo, float hi){
  return (unsigned)f2bf(lo) | ((unsigned)f2bf(hi) << 16);
}
DEV float tanh_fast(float x){
  x = fminf(fmaxf(x, -15.f), 15.f);
  float e = __expf(2.f * x);
  return (e - 1.f) / (e + 1.f);
}

// coherent (agent-scope, L3-backed) data path
#define AISSUE(dst, p) asm volatile("global_load_dwordx4 %0, %1, off sc0 sc1" : "=&v"(dst) : "v"(p) : "memory")
#define PLOAD(dst, p)  asm volatile("global_load_dword %0, %1, off"          : "=&v"(dst) : "v"(p) : "memory")
#define SC_STORE(p, v) asm volatile("global_store_dword %0, %1, off sc0 sc1" :: "v"(p), "v"(v) : "memory")
#define VWAIT(n)       asm volatile("s_waitcnt vmcnt(" #n ")" ::: "memory"); __builtin_amdgcn_sched_barrier(0)

DEV void poll_ge(unsigned* c, unsigned tgt){
  while (__hip_atomic_load(c, __ATOMIC_RELAXED, __HIP_MEMORY_SCOPE_AGENT) < tgt)
    __builtin_amdgcn_s_sleep(1);
}
DEV void arrive(unsigned* c){
  if ((threadIdx.x & 63) == 0)
    __hip_atomic_fetch_add(c, 1u, __ATOMIC_RELAXED, __HIP_MEMORY_SCOPE_AGENT);
}

// ---------------- weight prep (identical to R7) ----------------
__global__ __launch_bounds__(256) void k_prep(const float* __restrict__ Wf1, const float* __restrict__ Wg1,
                                              const float* __restrict__ Wf2, const float* __restrict__ Wg2,
                                              const float* __restrict__ Wl1, const float* __restrict__ Wl2,
                                              unsigned short* __restrict__ W1T, unsigned short* __restrict__ W2T,
                                              unsigned short* __restrict__ Wl1F, unsigned short* __restrict__ Wl2F){
  __shared__ float tl[32][33];
  const float* src; unsigned short* dst; int N; int fmt;
  switch (blockIdx.z){
    case 0: src = Wf1; dst = W1T;             N = 512; fmt = 0; break;
    case 1: src = Wg1; dst = W1T + 512*512;   N = 512; fmt = 0; break;
    case 2: src = Wf2; dst = W2T;             N = 512; fmt = 0; break;
    case 3: src = Wg2; dst = W2T + 512*512;   N = 512; fmt = 0; break;
    case 4: src = Wl1; dst = Wl1F;            N = 512; fmt = 1; break;
    default: src = Wl2; dst = Wl2F;           N = 64;  fmt = 2; break;
  }
  int k0 = blockIdx.x*32, n0 = blockIdx.y*32;
  if (n0 >= N) return;
  int tx = threadIdx.x, ty = threadIdx.y;     // block (32,8)
  #pragma unroll
  for (int r = 0; r < 4; r++) tl[ty + r*8][tx] = src[(size_t)(k0 + ty + r*8) * N + n0 + tx];
  __syncthreads();
  if (fmt == 0){
    int kpos = k0 + ((tx & 15)*2 + (tx >> 4));   // sigma perm within 32-block
    #pragma unroll
    for (int r = 0; r < 4; r++) dst[(size_t)(n0 + ty + r*8) * 512 + kpos] = f2bf(tl[tx][ty + r*8]);
  } else {
    int k = k0 + tx;
    int Nc = (fmt == 1) ? 512 : 64;
    #pragma unroll
    for (int r = 0; r < 4; r++){
      int col = n0 + ty + r*8;
      size_t idx = (((size_t)(k >> 5)*Nc + col)*4 + ((k >> 3) & 3))*8 + (k & 7);
      dst[idx] = f2bf(tl[tx][ty + r*8]);
    }
  }
}

__global__ void k_zero(unsigned* __restrict__ cnts){
  cnts[threadIdx.x + blockIdx.x*256] = 0u;
}

// one K-step of a 16-block MFMA pipeline (8-deep counted prefetch)
#define KSX(K, W) \
  VWAIT(W); \
  { short8 a_  = *(short8*)&ap[(K)&7]; \
    short8 b0_ = *(const short8*)(wbp + (K)*4096); \
    short8 b1_ = *(const short8*)(wbp + (K)*4096 + 1024); \
    p0 = __builtin_amdgcn_mfma_f32_16x16x32_bf16(a_, b0_, p0, 0,0,0); \
    p1 = __builtin_amdgcn_mfma_f32_16x16x32_bf16(a_, b1_, p1, 0,0,0); } \
  if ((K) < 8) { AISSUE(ap[(K)&7], abp + (size_t)((K)+8)*65536); }

#define RUN16X \
  AISSUE(ap[0], abp);          AISSUE(ap[1], abp+65536); \
  AISSUE(ap[2], abp+131072);   AISSUE(ap[3], abp+196608); \
  AISSUE(ap[4], abp+262144);   AISSUE(ap[5], abp+327680); \
  AISSUE(ap[6], abp+393216);   AISSUE(ap[7], abp+458752); \
  KSX( 0,7) KSX( 1,7) KSX( 2,7) KSX( 3,7) KSX( 4,7) KSX( 5,7) KSX( 6,7) KSX( 7,7) \
  KSX( 8,7) KSX( 9,6) KSX(10,5) KSX(11,4) KSX(12,3) KSX(13,2) KSX(14,1) KSX(15,0)

// ---------------- persistent scan v6: dual-crew offset pipelines ----------------
// 256 blocks x 512 thr. block b: pair=b&15 (rows pair*64..+63), ns=b>>4.
// crew c = w>>2 owns rows pair*64 + c*32 .. +31. Per crew: 4 waves,
// v=w&3: band=v&1 (16 rows), hr=v>>1 (P1: col-half of 64 u-cols; P2: 0=f,1=g).
// Crews cross-gated one phase apart: {P1A || P2B} then {P2A || P1B}.
__global__ __launch_bounds__(512, 1) void k_scan(
    const float* __restrict__ coeffs, const float* __restrict__ times,
    const float* __restrict__ dW,     const float* __restrict__ W_init,
    const float* __restrict__ b_init,
    const unsigned short* __restrict__ W1T, const unsigned short* __restrict__ W2T,
    const float* __restrict__ bf1, const float* __restrict__ bg1,
    const float* __restrict__ bf2, const float* __restrict__ bg2,
    unsigned short* __restrict__ ygk, unsigned short* __restrict__ uk,
    float* __restrict__ z, unsigned* __restrict__ cnts){
  __shared__ __align__(16) unsigned char W1s[65536];   // [16 kc][64 col][4 fq] x16B
  __shared__ __align__(16) unsigned char W2s[65536];   // col<32 f-slice, col>=32 g-slice
  __shared__ float cmb[2][32][33];                     // per-crew f-exchange (padded)
  __shared__ float x0s[64][66];
  __shared__ float tms[104];
  __shared__ unsigned fflag[4];                        // [crew*2+band]

  const int bid = blockIdx.x, pair = bid & 15, ns = bid >> 4;
  const int m0 = pair*64, n1 = ns*64, n2 = ns*32;
  const int tid = threadIdx.x, lane = tid & 63, w = tid >> 6;
  const int fr = lane & 15, fq = lane >> 4;
  const int crew = w >> 2, v = w & 3, band = v & 1, hr = v >> 1;
  const int rbase = m0 + crew*32 + band*16;

  // ---- stage weight slices into LDS (frag-major) ----
  #pragma unroll
  for (int i = 0; i < 8; i++){
    int u = i*512 + tid;                     // unit = (kc*64+cl)*4+fqi
    int fqi = u & 3, cl = (u >> 2) & 63, kc = u >> 8;
    *(uint4*)(W1s + (size_t)u*16) = *(const uint4*)(W1T + (size_t)(n1+cl)*512 + kc*32 + fqi*8);
    const unsigned short* s2 = (cl < 32) ? (W2T + (size_t)(n2+cl)*512)
                                         : (W2T + (size_t)262144 + (size_t)(n2+cl-32)*512);
    *(uint4*)(W2s + (size_t)u*16) = *(const uint4*)(s2 + kc*32 + fqi*8);
  }
  if (tid < 100) tms[tid] = times[tid];
  if (tid < 4)  fflag[tid] = 0u;
  { int row = tid >> 3, c0 = (tid & 7)*8;
    const float* src = coeffs + (size_t)(m0+row)*(TM1*4*64) + c0;
    *(float4*)(&x0s[row][c0])     = *(const float4*)src;
    *(float4*)(&x0s[row][c0 + 4]) = *(const float4*)(src + 4);
  }
  __syncthreads();

  // counters: cnts[pair*64 + {0:c1A,16:c1B,32:c2A,48:c2B}]
  unsigned* cbase = cnts + pair*64;
  unsigned* c1own = cbase + crew*16;
  unsigned* c1oth = cbase + (1-crew)*16;
  unsigned* c2own = cbase + 32 + crew*16;

  // per-lane pointers
  char* ygkb = (char*)ygk;
  char* ukb  = (char*)uk;
  const char* ab1 = ygkb + ((size_t)(rbase + fr))*64 + fq*16;
  const char* ab2 = ukb + (size_t)hr*1048576 + ((size_t)(rbase + fr))*64 + fq*16;
  char* up = ukb  + (size_t)(ns*2 + hr)*65536 + ((size_t)(rbase + fq*4))*64 + fr*4;
  char* yp = ygkb + (size_t)ns*65536          + ((size_t)(rbase + fq*4))*64 + fr*4;
  const unsigned char* wbp1 = W1s + (hr*32 + fr)*64 + fq*16;
  const unsigned char* wbp2 = W2s + (hr*32 + fr)*64 + fq*16;
  float* zp = z + ((size_t)(rbase + fq*4))*T*512 + n2 + fr;

  // biases
  const float* b1src = (ns < 8) ? bf1 : bg1;
  const int    b1off = n1 - ((ns < 8) ? 0 : 512) + hr*32 + fr;
  const float b1v0 = b1src[b1off], b1v1 = b1src[b1off + 16];
  const float* b2src = hr ? bg2 : bf2;
  const float b2v0 = b2src[n2 + fr], b2v1 = b2src[n2 + 16 + fr];

  // ---- init: g-waves (hr==1) compute y0 for their own P2 tile ----
  float yv[2][4];
  if (hr == 1){
    #pragma unroll
    for (int r = 0; r < 4; r++){
      int lrow = crew*32 + band*16 + fq*4 + r;
      float s0 = b_init[n2 + fr], s1 = b_init[n2 + 16 + fr];
      #pragma unroll 8
      for (int k = 0; k < 64; k++){
        float xv = x0s[lrow][k];
        s0 += xv * W_init[(size_t)k*512 + n2 + fr];
        s1 += xv * W_init[(size_t)k*512 + n2 + 16 + fr];
      }
      yv[0][r] = s0; yv[1][r] = s1;
      SC_STORE(yp + r*64, pack2(s0, s1));
    }
    #pragma unroll
    for (int r = 0; r < 4; r++){
      zp[(size_t)r*T*512]      = yv[0][r];
      zp[(size_t)r*T*512 + 16] = yv[1][r];
    }
    VWAIT(8);                                // drain the 4 y-sc stores
    arrive(c2own);
  }

  float dv[8];
  for (int t = 0; t < TM1; t++){
    VWAIT(0);                                // safety drain before polls
    // ===== P1 gates: own chain + cross-crew slot discipline =====
    poll_ge(c2own, 32u*(unsigned)(t+1));
    poll_ge(c1oth, 64u*(unsigned)t + 64u*(unsigned)crew);

    // ===== P1: u[rows 16][cols hr*32 + {fr,fr+16}] = tanh(y @ W1 + b1) =====
    {
      f32x4 p0 = {0.f,0.f,0.f,0.f}, p1 = {0.f,0.f,0.f,0.f};
      u32x4 ap[8];
      const char* abp = ab1;
      const unsigned char* wbp = wbp1;
      RUN16X;
      #pragma unroll
      for (int r = 0; r < 4; r++)
        SC_STORE(up + r*64, pack2(tanh_fast(p0[r] + b1v0), tanh_fast(p1[r] + b1v1)));
      if (hr == 1){                          // prefetch dW under the barrier window
        const char* dp = (const char*)dW + (((size_t)t*1024 + rbase + fq*4)*512 + n2 + fr)*4;
        PLOAD(dv[0], dp + 0);      PLOAD(dv[1], dp + 64);
        PLOAD(dv[2], dp + 2048);   PLOAD(dv[3], dp + 2048+64);
        PLOAD(dv[4], dp + 4096);   PLOAD(dv[5], dp + 4096+64);
        PLOAD(dv[6], dp + 6144);   PLOAD(dv[7], dp + 6144+64);
        VWAIT(8);                            // drain 4 u-sc (oldest); dW in flight
      } else {
        VWAIT(0);
      }
    }
    arrive(c1own);

    // ===== P2 gate =====
    poll_ge(c1own, 64u*(unsigned)(t+1));

    // ===== P2: hr==0 -> f-strip to LDS; hr==1 -> g-strip + y update =====
    {
      f32x4 p0 = {0.f,0.f,0.f,0.f}, p1 = {0.f,0.f,0.f,0.f};
      u32x4 ap[8];
      const char* abp = ab2;
      const unsigned char* wbp = wbp2;
      RUN16X;
      if (hr == 0){
        #pragma unroll
        for (int r = 0; r < 4; r++){
          int lrow = band*16 + fq*4 + r;
          cmb[crew][lrow][fr]      = p0[r] + b2v0;
          cmb[crew][lrow][fr + 16] = p1[r] + b2v1;
        }
        __hip_atomic_store(&fflag[crew*2 + band], (unsigned)(t+1),
                           __ATOMIC_RELEASE, __HIP_MEMORY_SCOPE_WORKGROUP);
      } else {
        while (__hip_atomic_load(&fflag[crew*2 + band], __ATOMIC_ACQUIRE,
                                 __HIP_MEMORY_SCOPE_WORKGROUP) < (unsigned)(t+1)) {}
        float h  = tms[t+1] - tms[t];
        float sq = sqrtf(h);
        float zn0[4], zn1[4];
        #pragma unroll
        for (int r = 0; r < 4; r++){
          int lrow = band*16 + fq*4 + r;
          float f0 = cmb[crew][lrow][fr], f1 = cmb[crew][lrow][fr + 16];
          float g0 = tanh_fast(p0[r] + b2v0), g1 = tanh_fast(p1[r] + b2v1);
          float y0n = yv[0][r] + f0*h + g0*(sq*dv[r*2]);
          float y1n = yv[1][r] + f1*h + g1*(sq*dv[r*2+1]);
          yv[0][r] = y0n; yv[1][r] = y1n;
          zn0[r] = y0n; zn1[r] = y1n;
          SC_STORE(yp + r*64, pack2(y0n, y1n));
        }
        #pragma unroll
        for (int r = 0; r < 4; r++){
          zp[(size_t)r*T*512 + (size_t)(t+1)*512]      = zn0[r];
          zp[(size_t)r*T*512 + (size_t)(t+1)*512 + 16] = zn1[r];
        }
        VWAIT(8);                            // drain 4 y-sc (oldest); z may linger
        arrive(c2own);
      }
    }
  }
}

// ---------------- fused readout (identical to R7) ----------------
__global__ __launch_bounds__(512, 1) void k_read(
    const float* __restrict__ z, const unsigned short* __restrict__ Wl1F,
    const float* __restrict__ bl1, const unsigned short* __restrict__ Wl2F,
    const float* __restrict__ bl2, float* __restrict__ out){
  __shared__ __align__(16) unsigned char zt[65536];
  __shared__ __align__(16) unsigned char relF[65536];
  const int tid = threadIdx.x, lane = tid & 63, w = tid >> 6;
  const int fr = lane & 15, fq = lane >> 4;
  const size_t rr0 = (size_t)blockIdx.x * 64;
  const int cw = w * 64;

  { int row = tid >> 3, c0 = (tid & 7) * 64;
    const float* zr = z + (rr0 + row) * 512 + c0;
    #pragma unroll
    for (int j = 0; j < 2; ++j){
      int kc = (c0 >> 5) + j;
      #pragma unroll
      for (int f = 0; f < 4; ++f){
        float4 v0 = *(const float4*)(zr + j*32 + f*8);
        float4 v1 = *(const float4*)(zr + j*32 + f*8 + 4);
        unsigned d0 = pack2(tanh_fast(v0.x), tanh_fast(v0.y));
        unsigned d1 = pack2(tanh_fast(v0.z), tanh_fast(v0.w));
        unsigned d2 = pack2(tanh_fast(v1.x), tanh_fast(v1.y));
        unsigned d3 = pack2(tanh_fast(v1.z), tanh_fast(v1.w));
        uint4 pk = {d0, d1, d2, d3};
        *(uint4*)(zt + (size_t)((kc*64 + row)*4 + f)*16) = pk;
      }
    }
  }
  __syncthreads();

  f32x4 acc[4][4];
  #pragma unroll
  for (int m = 0; m < 4; m++)
    #pragma unroll
    for (int c = 0; c < 4; c++) acc[m][c] = (f32x4){0.f,0.f,0.f,0.f};
  for (int kc = 0; kc < 16; ++kc){
    short8 a[4];
    #pragma unroll
    for (int m = 0; m < 4; m++)
      a[m] = *(const short8*)(zt + (size_t)((kc*64 + m*16 + fr)*4 + fq)*16);
    #pragma unroll
    for (int c = 0; c < 4; c++){
      short8 b = *(const short8*)(Wl1F + (((size_t)kc*512 + cw + c*16 + fr)*4 + fq)*8);
      #pragma unroll
      for (int m = 0; m < 4; m++)
        acc[m][c] = __builtin_amdgcn_mfma_f32_16x16x32_bf16(a[m], b, acc[m][c], 0, 0, 0);
    }
  }
  float bl1v[4];
  #pragma unroll
  for (int c = 0; c < 4; c++) bl1v[c] = bl1[cw + c*16 + fr];

  #pragma unroll
  for (int h = 0; h < 2; ++h){
    __syncthreads();
    if ((w >> 2) == h){
      float* stg = (float*)zt;
      int cb = cw - h*256;
      #pragma unroll
      for (int m = 0; m < 4; m++)
        #pragma unroll
        for (int c = 0; c < 4; c++)
          #pragma unroll
          for (int r = 0; r < 4; r++)
            stg[(m*16 + fq*4 + r)*256 + cb + c*16 + fr] = fmaxf(acc[m][c][r] + bl1v[c], 0.f);
    }
    __syncthreads();
    { int row = tid >> 3, c8 = (tid & 7) * 32;
      const float* stg = (const float*)zt;
      int kc = h*8 + (tid & 7);
      #pragma unroll
      for (int f = 0; f < 4; ++f){
        const float* p = stg + row*256 + c8 + f*8;
        unsigned d0 = pack2(p[0], p[1]);
        unsigned d1 = pack2(p[2], p[3]);
        unsigned d2 = pack2(p[4], p[5]);
        unsigned d3 = pack2(p[6], p[7]);
        uint4 pk = {d0, d1, d2, d3};
        *(uint4*)(relF + (size_t)((kc*64 + row)*4 + f)*16) = pk;
      }
    }
  }
  __syncthreads();

  f32x4 acc2[2];
  acc2[0] = (f32x4){0.f,0.f,0.f,0.f};
  acc2[1] = (f32x4){0.f,0.f,0.f,0.f};
  const int mt2 = w & 3, ocb = (w >> 2) * 32;
  for (int kc = 0; kc < 16; ++kc){
    short8 a = *(const short8*)(relF + (size_t)((kc*64 + mt2*16 + fr)*4 + fq)*16);
    #pragma unroll
    for (int j = 0; j < 2; j++){
      short8 b = *(const short8*)(Wl2F + (((size_t)(kc*64 + ocb + j*16 + fr))*4 + fq)*8);
      acc2[j] = __builtin_amdgcn_mfma_f32_16x16x32_bf16(a, b, acc2[j], 0, 0, 0);
    }
  }
  #pragma unroll
  for (int j = 0; j < 2; j++){
    #pragma unroll
    for (int r = 0; r < 4; r++){
      int row = mt2*16 + fq*4 + r;
      int oc  = ocb + j*16 + fr;
      out[(rr0 + row)*64 + oc] = acc2[j][r] + bl2[oc];
    }
  }
}

extern "C" void kernel_launch(void* const* d_in, const int* in_sizes, int n_in,
                              void* d_out, int out_size, void* d_ws, size_t ws_size,
                              hipStream_t stream){
  (void)in_sizes; (void)n_in; (void)out_size; (void)ws_size;
  const float* coeffs = (const float*)d_in[0];
  const float* times  = (const float*)d_in[1];
  const float* dW     = (const float*)d_in[2];
  const float* W_init = (const float*)d_in[3];
  const float* b_init = (const float*)d_in[4];
  const float* Wf1 = (const float*)d_in[5];
  const float* bf1 = (const float*)d_in[6];
  const float* Wf2 = (const float*)d_in[7];
  const float* bf2 = (const float*)d_in[8];
  const float* Wg1 = (const float*)d_in[9];
  const float* bg1 = (const float*)d_in[10];
  const float* Wg2 = (const float*)d_in[11];
  const float* bg2 = (const float*)d_in[12];
  const float* Wl1 = (const float*)d_in[13];
  const float* bl1 = (const float*)d_in[14];
  const float* Wl2 = (const float*)d_in[15];
  const float* bl2 = (const float*)d_in[16];

  float* out = (float*)d_out;
  float* z   = out + (size_t)Bsz * T * OUTD;   // z region of d_out, (B,T,H)

  char* wsp = (char*)d_ws;
  auto carve = [&](size_t bytes) -> void* {
    void* p = (void*)wsp; wsp += (bytes + 255) & ~(size_t)255; return p;
  };
  unsigned short* W1T  = (unsigned short*)carve((size_t)H2 * H * 2);
  unsigned short* W2T  = (unsigned short*)carve((size_t)H2 * H * 2);
  unsigned short* Wl1F = (unsigned short*)carve((size_t)H * H * 2);
  unsigned short* Wl2F = (unsigned short*)carve((size_t)OUTD * H * 2);
  unsigned short* ygk  = (unsigned short*)carve((size_t)Bsz * H * 2);   // [16][1024][32]
  unsigned short* uk   = (unsigned short*)carve((size_t)Bsz * H2 * 2);  // [32][1024][32]
  unsigned*       cnts = (unsigned*)carve(1024 * sizeof(unsigned));

  k_zero<<<dim3(4), 256, 0, stream>>>(cnts);
  k_prep<<<dim3(16, 16, 6), dim3(32, 8), 0, stream>>>(Wf1, Wg1, Wf2, Wg2, Wl1, Wl2,
                                                      W1T, W2T, Wl1F, Wl2F);
  k_scan<<<dim3(256), 512, 0, stream>>>(coeffs, times, dW, W_init, b_init,
                                        W1T, W2T, bf1, bg1, bf2, bg2,
                                        ygk, uk, z, cnts);
  k_read<<<dim3(BT / 64), 512, 0, stream>>>(z, Wl1F, bl1, Wl2F, bl2, out);
}

// Round 9
// 937.224 us; speedup vs baseline: 2.9045x; 2.9045x over previous
//
#include <hip/hip_runtime.h>
#include <hip/hip_bf16.h>
#include <math.h>

#define DEV __device__ __forceinline__

typedef __attribute__((ext_vector_type(8))) short short8;
typedef __attribute__((ext_vector_type(4))) float f32x4;
typedef __attribute__((ext_vector_type(4))) unsigned int u32x4;

static constexpr int Bsz  = 1024;
static constexpr int T    = 100;
static constexpr int TM1  = 99;
static constexpr int H    = 512;
static constexpr int OUTD = 64;
static constexpr int H2   = 1024;
static constexpr int BT   = Bsz * T;        // 102400

DEV unsigned short f2bf(float f){
  unsigned int u = __float_as_uint(f);
  u += 0x7fffu + ((u >> 16) & 1u);          // round-to-nearest-even
  return (unsigned short)(u >> 16);
}
DEV unsigned pack2(float lo, float hi){
  return (unsigned)f2bf(lo) | ((unsigned)f2bf(hi) << 16);
}
DEV float tanh_fast(float x){
  x = fminf(fmaxf(x, -15.f), 15.f);
  float e = __expf(2.f * x);
  return (e - 1.f) / (e + 1.f);
}

// data-path asm:
//  AISSUE_CC: L3-coherent load (addresses reused across steps -> must bypass L2)
//  AISSUE_L2: L2-cacheable load (write-once addresses -> staleness impossible)
#define AISSUE_CC(dst, p) asm volatile("global_load_dwordx4 %0, %1, off sc0 sc1" : "=&v"(dst) : "v"(p) : "memory")
#define AISSUE_L2(dst, p) asm volatile("global_load_dwordx4 %0, %1, off sc0"     : "=&v"(dst) : "v"(p) : "memory")
#define PLOAD(dst, p)  asm volatile("global_load_dword %0, %1, off"          : "=&v"(dst) : "v"(p) : "memory")
#define SC_STORE(p, v) asm volatile("global_store_dword %0, %1, off sc0 sc1" :: "v"(p), "v"(v) : "memory")
#define VWAIT(n)       asm volatile("s_waitcnt vmcnt(" #n ")" ::: "memory"); __builtin_amdgcn_sched_barrier(0)

// fence-free 16-block group barrier; callers drain their sc-stores (counted vmcnt) first
DEV void gbar(unsigned* cnt, unsigned target){
  __syncthreads();
  if (threadIdx.x == 0){
    __hip_atomic_fetch_add(cnt, 1u, __ATOMIC_RELAXED, __HIP_MEMORY_SCOPE_AGENT);
    while (__hip_atomic_load(cnt, __ATOMIC_RELAXED, __HIP_MEMORY_SCOPE_AGENT) < target)
      __builtin_amdgcn_s_sleep(1);
  }
  __syncthreads();
}

// ---------------- weight prep (identical to R7) ----------------
__global__ __launch_bounds__(256) void k_prep(const float* __restrict__ Wf1, const float* __restrict__ Wg1,
                                              const float* __restrict__ Wf2, const float* __restrict__ Wg2,
                                              const float* __restrict__ Wl1, const float* __restrict__ Wl2,
                                              unsigned short* __restrict__ W1T, unsigned short* __restrict__ W2T,
                                              unsigned short* __restrict__ Wl1F, unsigned short* __restrict__ Wl2F){
  __shared__ float tl[32][33];
  const float* src; unsigned short* dst; int N; int fmt;
  switch (blockIdx.z){
    case 0: src = Wf1; dst = W1T;             N = 512; fmt = 0; break;
    case 1: src = Wg1; dst = W1T + 512*512;   N = 512; fmt = 0; break;
    case 2: src = Wf2; dst = W2T;             N = 512; fmt = 0; break;
    case 3: src = Wg2; dst = W2T + 512*512;   N = 512; fmt = 0; break;
    case 4: src = Wl1; dst = Wl1F;            N = 512; fmt = 1; break;
    default: src = Wl2; dst = Wl2F;           N = 64;  fmt = 2; break;
  }
  int k0 = blockIdx.x*32, n0 = blockIdx.y*32;
  if (n0 >= N) return;
  int tx = threadIdx.x, ty = threadIdx.y;     // block (32,8)
  #pragma unroll
  for (int r = 0; r < 4; r++) tl[ty + r*8][tx] = src[(size_t)(k0 + ty + r*8) * N + n0 + tx];
  __syncthreads();
  if (fmt == 0){
    int kpos = k0 + ((tx & 15)*2 + (tx >> 4));   // sigma perm within 32-block
    #pragma unroll
    for (int r = 0; r < 4; r++) dst[(size_t)(n0 + ty + r*8) * 512 + kpos] = f2bf(tl[tx][ty + r*8]);
  } else {
    int k = k0 + tx;
    int Nc = (fmt == 1) ? 512 : 64;
    #pragma unroll
    for (int r = 0; r < 4; r++){
      int col = n0 + ty + r*8;
      size_t idx = (((size_t)(k >> 5)*Nc + col)*4 + ((k >> 3) & 3))*8 + (k & 7);
      dst[idx] = f2bf(tl[tx][ty + r*8]);
    }
  }
}

__global__ void k_zero(unsigned* __restrict__ cnts){
  cnts[threadIdx.x + blockIdx.x*256] = 0u;
}

// one K-step of a 16-block MFMA pipeline (8-deep counted prefetch), LD = load macro
#define KSX(K, W, LD) \
  VWAIT(W); \
  { short8 a_  = *(short8*)&ap[(K)&7]; \
    short8 b0_ = *(const short8*)(wbp + (K)*4096); \
    short8 b1_ = *(const short8*)(wbp + (K)*4096 + 1024); \
    p0 = __builtin_amdgcn_mfma_f32_16x16x32_bf16(a_, b0_, p0, 0,0,0); \
    p1 = __builtin_amdgcn_mfma_f32_16x16x32_bf16(a_, b1_, p1, 0,0,0); } \
  if ((K) < 8) { LD(ap[(K)&7], abp + (size_t)((K)+8)*65536); }

#define RUN16X(LD) \
  LD(ap[0], abp);          LD(ap[1], abp+65536); \
  LD(ap[2], abp+131072);   LD(ap[3], abp+196608); \
  LD(ap[4], abp+262144);   LD(ap[5], abp+327680); \
  LD(ap[6], abp+393216);   LD(ap[7], abp+458752); \
  KSX( 0,7,LD) KSX( 1,7,LD) KSX( 2,7,LD) KSX( 3,7,LD) \
  KSX( 4,7,LD) KSX( 5,7,LD) KSX( 6,7,LD) KSX( 7,7,LD) \
  KSX( 8,7,LD) KSX( 9,6,LD) KSX(10,5,LD) KSX(11,4,LD) \
  KSX(12,3,LD) KSX(13,2,LD) KSX(14,1,LD) KSX(15,0,LD)

// ---------------- persistent group-synced scan v7 ----------------
// R6 protocol (block-level barrier), 8-deep prefetch, dW under barrier.
// UNIQ=1: y/u step-unique (write-once addresses) -> A-loads L2-cacheable (sc0).
// UNIQ=0: single y/u buffers -> A-loads L3-coherent (sc0 sc1). Picked by ws_size.
template<int UNIQ>
__global__ __launch_bounds__(512, 1) void k_scan(
    const float* __restrict__ coeffs, const float* __restrict__ times,
    const float* __restrict__ dW,     const float* __restrict__ W_init,
    const float* __restrict__ b_init,
    const unsigned short* __restrict__ W1T, const unsigned short* __restrict__ W2T,
    const float* __restrict__ bf1, const float* __restrict__ bg1,
    const float* __restrict__ bf2, const float* __restrict__ bg2,
    unsigned short* __restrict__ ygk, unsigned short* __restrict__ uk,
    float* __restrict__ z, unsigned* __restrict__ cnts){
  __shared__ __align__(16) unsigned char W1s[65536];   // [16 kc][64 col][4 fq] x16B
  __shared__ __align__(16) unsigned char W2s[65536];   // col<32 f-slice, col>=32 g-slice
  __shared__ __align__(16) float cmb[64*68];           // x0 stage / f-result exchange
  __shared__ float tms[104];

  constexpr size_t YB = UNIQ ? (size_t)Bsz * H  * 2 : 0;   // 1 MB per step
  constexpr size_t UB = UNIQ ? (size_t)Bsz * H2 * 2 : 0;   // 2 MB per step

  const int bid = blockIdx.x, mt = bid & 15, ns = bid >> 4;
  const int m0 = mt*64, n1 = ns*64, n2 = ns*32;
  const int tid = threadIdx.x, lane = tid & 63, w = tid >> 6;
  const int fr = lane & 15, fq = lane >> 4;
  const int band = w & 3, isg = w >> 2;
  unsigned* cnt = cnts + mt*32;
  unsigned ep = 0;

  // ---- stage weight slices into LDS (frag-major) ----
  #pragma unroll
  for (int i = 0; i < 8; i++){
    int u = i*512 + tid;                     // unit = (kc*64+cl)*4+fqi
    int fqi = u & 3, cl = (u >> 2) & 63, kc = u >> 8;
    *(uint4*)(W1s + (size_t)u*16) = *(const uint4*)(W1T + (size_t)(n1+cl)*512 + kc*32 + fqi*8);
    const unsigned short* s2 = (cl < 32) ? (W2T + (size_t)(n2+cl)*512)
                                         : (W2T + (size_t)262144 + (size_t)(n2+cl-32)*512);
    *(uint4*)(W2s + (size_t)u*16) = *(const uint4*)(s2 + kc*32 + fqi*8);
  }
  if (tid < 100) tms[tid] = times[tid];
  { int row = tid >> 3, c0 = (tid & 7)*8;
    const float* src = coeffs + (size_t)(m0+row)*(TM1*4*64) + c0;
    *(float4*)(&cmb[row*68 + c0])     = *(const float4*)src;
    *(float4*)(&cmb[row*68 + c0 + 4]) = *(const float4*)(src + 4);
  }
  __syncthreads();

  // per-lane pointers (base of step-0 buffers)
  char* ygkb = (char*)ygk;
  char* ukb  = (char*)uk;
  const char* ab1 = ygkb + ((size_t)(m0 + band*16 + fr))*64 + fq*16;
  const char* ab2 = ukb + (size_t)isg*1048576 + ((size_t)(m0 + band*16 + fr))*64 + fq*16;
  char* up = ukb  + (size_t)(ns*2 + isg)*65536 + ((size_t)(m0 + band*16 + fq*4))*64 + fr*4;
  char* yp = ygkb + (size_t)ns*65536           + ((size_t)(m0 + band*16 + fq*4))*64 + fr*4;
  const unsigned char* wbp1 = W1s + isg*2048 + fr*64 + fq*16;
  const unsigned char* wbp2 = W2s + isg*2048 + fr*64 + fq*16;
  float* zp = z + ((size_t)(m0 + band*16 + fq*4))*T*512 + n2 + fr;

  // biases
  const float* b1src = (ns < 8) ? bf1 : bg1;
  const int    b1off = n1 - ((ns < 8) ? 0 : 512) + isg*32 + fr;
  const float b1v0 = b1src[b1off], b1v1 = b1src[b1off + 16];
  const float* b2src = isg ? bg2 : bf2;
  const float b2v0 = b2src[n2 + fr], b2v1 = b2src[n2 + 16 + fr];

  // ---- init: y0 = x0 @ W_init + b_init (g-waves own y slice) -> y buffer 0 ----
  float yv[2][4];
  if (isg){
    #pragma unroll
    for (int r = 0; r < 4; r++){
      int lrow = band*16 + fq*4 + r;
      float s0 = b_init[n2 + fr], s1 = b_init[n2 + 16 + fr];
      #pragma unroll 8
      for (int k = 0; k < 64; k++){
        float xv = cmb[lrow*68 + k];
        s0 += xv * W_init[(size_t)k*512 + n2 + fr];
        s1 += xv * W_init[(size_t)k*512 + n2 + 16 + fr];
      }
      yv[0][r] = s0; yv[1][r] = s1;
      SC_STORE(yp + r*64, pack2(s0, s1));
      zp[(size_t)r*T*512]      = s0;
      zp[(size_t)r*T*512 + 16] = s1;
    }
    VWAIT(8);                                // 4 y-sc complete; z may linger
  }
  ++ep; gbar(cnt, ep*16);

  for (int t = 0; t < TM1; t++){
    float dv[8];
    // ===== phase 1: u(t) = tanh(y(t) @ W1 + b1); dW prefetch under barrier =====
    {
      f32x4 p0 = {0.f,0.f,0.f,0.f}, p1 = {0.f,0.f,0.f,0.f};
      u32x4 ap[8];
      const char* abp = ab1 + (size_t)t*YB;
      const unsigned char* wbp = wbp1;
      if constexpr (UNIQ) { RUN16X(AISSUE_L2); } else { RUN16X(AISSUE_CC); }
      char* upt = up + (size_t)t*UB;
      #pragma unroll
      for (int r = 0; r < 4; r++)
        SC_STORE(upt + r*64, pack2(tanh_fast(p0[r] + b1v0), tanh_fast(p1[r] + b1v1)));
      if (isg){
        const char* dp = (const char*)dW + (((size_t)t*1024 + m0 + band*16 + fq*4)*512 + n2 + fr)*4;
        PLOAD(dv[0], dp + 0);      PLOAD(dv[1], dp + 64);
        PLOAD(dv[2], dp + 2048);   PLOAD(dv[3], dp + 2048+64);
        PLOAD(dv[4], dp + 4096);   PLOAD(dv[5], dp + 4096+64);
        PLOAD(dv[6], dp + 6144);   PLOAD(dv[7], dp + 6144+64);
        VWAIT(8);                            // 4 u-sc complete; dW in flight
      } else {
        VWAIT(0);
      }
    }
    ++ep; gbar(cnt, ep*16);

    // ===== phase 2: f-waves u_f@Wf2 -> cmb; g-waves u_g@Wg2 + y update =====
    {
      f32x4 p0 = {0.f,0.f,0.f,0.f}, p1 = {0.f,0.f,0.f,0.f};
      u32x4 ap[8];
      const char* abp = ab2 + (size_t)t*UB;
      const unsigned char* wbp = wbp2;
      if constexpr (UNIQ) { RUN16X(AISSUE_L2); } else { RUN16X(AISSUE_CC); }
      if (!isg){
        #pragma unroll
        for (int r = 0; r < 4; r++){
          int lrow = band*16 + fq*4 + r;
          cmb[lrow*68 + fr]      = p0[r] + b2v0;
          cmb[lrow*68 + 16 + fr] = p1[r] + b2v1;
        }
      }
      __syncthreads();
      if (isg){
        float h  = tms[t+1] - tms[t];
        float sq = sqrtf(h);
        char* ypt = yp + (size_t)(t+1)*YB;
        #pragma unroll
        for (int r = 0; r < 4; r++){
          int lrow = band*16 + fq*4 + r;
          float f0 = cmb[lrow*68 + fr],       f1 = cmb[lrow*68 + 16 + fr];
          float g0 = tanh_fast(p0[r] + b2v0), g1 = tanh_fast(p1[r] + b2v1);
          float y0n = yv[0][r] + f0*h + g0*(sq*dv[r*2]);
          float y1n = yv[1][r] + f1*h + g1*(sq*dv[r*2+1]);
          yv[0][r] = y0n; yv[1][r] = y1n;
          SC_STORE(ypt + r*64, pack2(y0n, y1n));
          zp[(size_t)r*T*512 + (size_t)(t+1)*512]      = y0n;
          zp[(size_t)r*T*512 + (size_t)(t+1)*512 + 16] = y1n;
        }
        VWAIT(8);                            // 4 y-sc complete; z may linger
      }
    }
    if (t < TM1-1){ ++ep; gbar(cnt, ep*16); }
  }
}

// ---------------- fused readout (identical to R7) ----------------
__global__ __launch_bounds__(512, 1) void k_read(
    const float* __restrict__ z, const unsigned short* __restrict__ Wl1F,
    const float* __restrict__ bl1, const unsigned short* __restrict__ Wl2F,
    const float* __restrict__ bl2, float* __restrict__ out){
  __shared__ __align__(16) unsigned char zt[65536];
  __shared__ __align__(16) unsigned char relF[65536];
  const int tid = threadIdx.x, lane = tid & 63, w = tid >> 6;
  const int fr = lane & 15, fq = lane >> 4;
  const size_t rr0 = (size_t)blockIdx.x * 64;
  const int cw = w * 64;

  { int row = tid >> 3, c0 = (tid & 7) * 64;
    const float* zr = z + (rr0 + row) * 512 + c0;
    #pragma unroll
    for (int j = 0; j < 2; ++j){
      int kc = (c0 >> 5) + j;
      #pragma unroll
      for (int f = 0; f < 4; ++f){
        float4 v0 = *(const float4*)(zr + j*32 + f*8);
        float4 v1 = *(const float4*)(zr + j*32 + f*8 + 4);
        unsigned d0 = pack2(tanh_fast(v0.x), tanh_fast(v0.y));
        unsigned d1 = pack2(tanh_fast(v0.z), tanh_fast(v0.w));
        unsigned d2 = pack2(tanh_fast(v1.x), tanh_fast(v1.y));
        unsigned d3 = pack2(tanh_fast(v1.z), tanh_fast(v1.w));
        uint4 pk = {d0, d1, d2, d3};
        *(uint4*)(zt + (size_t)((kc*64 + row)*4 + f)*16) = pk;
      }
    }
  }
  __syncthreads();

  f32x4 acc[4][4];
  #pragma unroll
  for (int m = 0; m < 4; m++)
    #pragma unroll
    for (int c = 0; c < 4; c++) acc[m][c] = (f32x4){0.f,0.f,0.f,0.f};
  for (int kc = 0; kc < 16; ++kc){
    short8 a[4];
    #pragma unroll
    for (int m = 0; m < 4; m++)
      a[m] = *(const short8*)(zt + (size_t)((kc*64 + m*16 + fr)*4 + fq)*16);
    #pragma unroll
    for (int c = 0; c < 4; c++){
      short8 b = *(const short8*)(Wl1F + (((size_t)kc*512 + cw + c*16 + fr)*4 + fq)*8);
      #pragma unroll
      for (int m = 0; m < 4; m++)
        acc[m][c] = __builtin_amdgcn_mfma_f32_16x16x32_bf16(a[m], b, acc[m][c], 0, 0, 0);
    }
  }
  float bl1v[4];
  #pragma unroll
  for (int c = 0; c < 4; c++) bl1v[c] = bl1[cw + c*16 + fr];

  #pragma unroll
  for (int h = 0; h < 2; ++h){
    __syncthreads();
    if ((w >> 2) == h){
      float* stg = (float*)zt;
      int cb = cw - h*256;
      #pragma unroll
      for (int m = 0; m < 4; m++)
        #pragma unroll
        for (int c = 0; c < 4; c++)
          #pragma unroll
          for (int r = 0; r < 4; r++)
            stg[(m*16 + fq*4 + r)*256 + cb + c*16 + fr] = fmaxf(acc[m][c][r] + bl1v[c], 0.f);
    }
    __syncthreads();
    { int row = tid >> 3, c8 = (tid & 7) * 32;
      const float* stg = (const float*)zt;
      int kc = h*8 + (tid & 7);
      #pragma unroll
      for (int f = 0; f < 4; ++f){
        const float* p = stg + row*256 + c8 + f*8;
        unsigned d0 = pack2(p[0], p[1]);
        unsigned d1 = pack2(p[2], p[3]);
        unsigned d2 = pack2(p[4], p[5]);
        unsigned d3 = pack2(p[6], p[7]);
        uint4 pk = {d0, d1, d2, d3};
        *(uint4*)(relF + (size_t)((kc*64 + row)*4 + f)*16) = pk;
      }
    }
  }
  __syncthreads();

  f32x4 acc2[2];
  acc2[0] = (f32x4){0.f,0.f,0.f,0.f};
  acc2[1] = (f32x4){0.f,0.f,0.f,0.f};
  const int mt2 = w & 3, ocb = (w >> 2) * 32;
  for (int kc = 0; kc < 16; ++kc){
    short8 a = *(const short8*)(relF + (size_t)((kc*64 + mt2*16 + fr)*4 + fq)*16);
    #pragma unroll
    for (int j = 0; j < 2; j++){
      short8 b = *(const short8*)(Wl2F + (((size_t)(kc*64 + ocb + j*16 + fr))*4 + fq)*8);
      acc2[j] = __builtin_amdgcn_mfma_f32_16x16x32_bf16(a, b, acc2[j], 0, 0, 0);
    }
  }
  #pragma unroll
  for (int j = 0; j < 2; j++){
    #pragma unroll
    for (int r = 0; r < 4; r++){
      int row = mt2*16 + fq*4 + r;
      int oc  = ocb + j*16 + fr;
      out[(rr0 + row)*64 + oc] = acc2[j][r] + bl2[oc];
    }
  }
}

extern "C" void kernel_launch(void* const* d_in, const int* in_sizes, int n_in,
                              void* d_out, int out_size, void* d_ws, size_t ws_size,
                              hipStream_t stream){
  (void)in_sizes; (void)n_in; (void)out_size;
  const float* coeffs = (const float*)d_in[0];
  const float* times  = (const float*)d_in[1];
  const float* dW     = (const float*)d_in[2];
  const float* W_init = (const float*)d_in[3];
  const float* b_init = (const float*)d_in[4];
  const float* Wf1 = (const float*)d_in[5];
  const float* bf1 = (const float*)d_in[6];
  const float* Wf2 = (const float*)d_in[7];
  const float* bf2 = (const float*)d_in[8];
  const float* Wg1 = (const float*)d_in[9];
  const float* bg1 = (const float*)d_in[10];
  const float* Wg2 = (const float*)d_in[11];
  const float* bg2 = (const float*)d_in[12];
  const float* Wl1 = (const float*)d_in[13];
  const float* bl1 = (const float*)d_in[14];
  const float* Wl2 = (const float*)d_in[15];
  const float* bl2 = (const float*)d_in[16];

  float* out = (float*)d_out;
  float* z   = out + (size_t)Bsz * T * OUTD;   // z region of d_out, (B,T,H)

  // step-unique layout needs ~302 MB of workspace
  const bool full = ws_size >= ((size_t)320 << 20);

  char* wsp = (char*)d_ws;
  auto carve = [&](size_t bytes) -> void* {
    void* p = (void*)wsp; wsp += (bytes + 255) & ~(size_t)255; return p;
  };
  unsigned short* W1T  = (unsigned short*)carve((size_t)H2 * H * 2);
  unsigned short* W2T  = (unsigned short*)carve((size_t)H2 * H * 2);
  unsigned short* Wl1F = (unsigned short*)carve((size_t)H * H * 2);
  unsigned short* Wl2F = (unsigned short*)carve((size_t)OUTD * H * 2);
  unsigned short* ygk  = (unsigned short*)carve(full ? (size_t)T   * Bsz * H  * 2
                                                     : (size_t)Bsz * H  * 2);
  unsigned short* uk   = (unsigned short*)carve(full ? (size_t)TM1 * Bsz * H2 * 2
                                                     : (size_t)Bsz * H2 * 2);
  unsigned*       cnts = (unsigned*)carve(1024 * sizeof(unsigned));

  k_zero<<<dim3(4), 256, 0, stream>>>(cnts);
  k_prep<<<dim3(16, 16, 6), dim3(32, 8), 0, stream>>>(Wf1, Wg1, Wf2, Wg2, Wl1, Wl2,
                                                      W1T, W2T, Wl1F, Wl2F);
  if (full)
    k_scan<1><<<dim3(256), 512, 0, stream>>>(coeffs, times, dW, W_init, b_init,
                                             W1T, W2T, bf1, bg1, bf2, bg2,
                                             ygk, uk, z, cnts);
  else
    k_scan<0><<<dim3(256), 512, 0, stream>>>(coeffs, times, dW, W_init, b_init,
                                             W1T, W2T, bf1, bg1, bf2, bg2,
                                             ygk, uk, z, cnts);
  k_read<<<dim3(BT / 64), 512, 0, stream>>>(z, Wl1F, bl1, Wl2F, bl2, out);
}

// Round 13
// 930.910 us; speedup vs baseline: 2.9242x; 1.0068x over previous
//
#include <hip/hip_runtime.h>
#include <hip/hip_bf16.h>
#include <math.h>

#define DEV __device__ __forceinline__

typedef __attribute__((ext_vector_type(8))) short short8;
typedef __attribute__((ext_vector_type(4))) float f32x4;
typedef __attribute__((ext_vector_type(4))) unsigned int u32x4;

static constexpr int Bsz  = 1024;
static constexpr int T    = 100;
static constexpr int TM1  = 99;
static constexpr int H    = 512;
static constexpr int OUTD = 64;
static constexpr int H2   = 1024;
static constexpr int BT   = Bsz * T;        // 102400

DEV unsigned short f2bf(float f){
  unsigned int u = __float_as_uint(f);
  u += 0x7fffu + ((u >> 16) & 1u);          // round-to-nearest-even
  return (unsigned short)(u >> 16);
}
DEV unsigned pack2(float lo, float hi){
  return (unsigned)f2bf(lo) | ((unsigned)f2bf(hi) << 16);
}
DEV float tanh_fast(float x){
  x = fminf(fmaxf(x, -15.f), 15.f);
  float e = __expf(2.f * x);
  return (e - 1.f) / (e + 1.f);
}

// data-path asm:
//  AISSUE_CC: L3-coherent load (addresses reused across steps -> must bypass L2)
//  AISSUE_L2: L2-cacheable load (write-once addresses -> staleness impossible)
#define AISSUE_CC(dst, p) asm volatile("global_load_dwordx4 %0, %1, off sc0 sc1" : "=&v"(dst) : "v"(p) : "memory")
#define AISSUE_L2(dst, p) asm volatile("global_load_dwordx4 %0, %1, off sc0"     : "=&v"(dst) : "v"(p) : "memory")
#define PLOAD(dst, p)  asm volatile("global_load_dword %0, %1, off"          : "=&v"(dst) : "v"(p) : "memory")
#define SC_STORE(p, v) asm volatile("global_store_dword %0, %1, off sc0 sc1" :: "v"(p), "v"(v) : "memory")
#define VWAIT(n)       asm volatile("s_waitcnt vmcnt(" #n ")" ::: "memory"); __builtin_amdgcn_sched_barrier(0)

// fence-free 16-block group barrier, split into arrive/wait so independent
// work (own-chunk A-load pre-issue) can overlap the poll.
DEV void gbar_arrive(unsigned* cnt){
  __syncthreads();
  if (threadIdx.x == 0)
    __hip_atomic_fetch_add(cnt, 1u, __ATOMIC_RELAXED, __HIP_MEMORY_SCOPE_AGENT);
}
DEV void gbar_wait(unsigned* cnt, unsigned target){
  if (threadIdx.x == 0){
    while (__hip_atomic_load(cnt, __ATOMIC_RELAXED, __HIP_MEMORY_SCOPE_AGENT) < target)
      __builtin_amdgcn_s_sleep(1);
  }
  __syncthreads();
}

// ---------------- weight prep (identical to R9) ----------------
__global__ __launch_bounds__(256) void k_prep(const float* __restrict__ Wf1, const float* __restrict__ Wg1,
                                              const float* __restrict__ Wf2, const float* __restrict__ Wg2,
                                              const float* __restrict__ Wl1, const float* __restrict__ Wl2,
                                              unsigned short* __restrict__ W1T, unsigned short* __restrict__ W2T,
                                              unsigned short* __restrict__ Wl1F, unsigned short* __restrict__ Wl2F){
  __shared__ float tl[32][33];
  const float* src; unsigned short* dst; int N; int fmt;
  switch (blockIdx.z){
    case 0: src = Wf1; dst = W1T;             N = 512; fmt = 0; break;
    case 1: src = Wg1; dst = W1T + 512*512;   N = 512; fmt = 0; break;
    case 2: src = Wf2; dst = W2T;             N = 512; fmt = 0; break;
    case 3: src = Wg2; dst = W2T + 512*512;   N = 512; fmt = 0; break;
    case 4: src = Wl1; dst = Wl1F;            N = 512; fmt = 1; break;
    default: src = Wl2; dst = Wl2F;           N = 64;  fmt = 2; break;
  }
  int k0 = blockIdx.x*32, n0 = blockIdx.y*32;
  if (n0 >= N) return;
  int tx = threadIdx.x, ty = threadIdx.y;     // block (32,8)
  #pragma unroll
  for (int r = 0; r < 4; r++) tl[ty + r*8][tx] = src[(size_t)(k0 + ty + r*8) * N + n0 + tx];
  __syncthreads();
  if (fmt == 0){
    int kpos = k0 + ((tx & 15)*2 + (tx >> 4));   // sigma perm within 32-block
    #pragma unroll
    for (int r = 0; r < 4; r++) dst[(size_t)(n0 + ty + r*8) * 512 + kpos] = f2bf(tl[tx][ty + r*8]);
  } else {
    int k = k0 + tx;
    int Nc = (fmt == 1) ? 512 : 64;
    #pragma unroll
    for (int r = 0; r < 4; r++){
      int col = n0 + ty + r*8;
      size_t idx = (((size_t)(k >> 5)*Nc + col)*4 + ((k >> 3) & 3))*8 + (k & 7);
      dst[idx] = f2bf(tl[tx][ty + r*8]);
    }
  }
}

__global__ void k_zero(unsigned* __restrict__ cnts){
  cnts[threadIdx.x + blockIdx.x*256] = 0u;
}

// ---- unrotated 16-chunk pipeline (phase 2), B from swizzled LDS ----
#define KSX(K, W, LD) \
  VWAIT(W); \
  { short8 a_  = *(short8*)&ap[(K)&7]; \
    short8 b0_ = *(const short8*)(wbp + (size_t)(K)*4096); \
    short8 b1_ = *(const short8*)(wbp + (size_t)(K)*4096 + 1024); \
    p0 = __builtin_amdgcn_mfma_f32_16x16x32_bf16(a_, b0_, p0, 0,0,0); \
    p1 = __builtin_amdgcn_mfma_f32_16x16x32_bf16(a_, b1_, p1, 0,0,0); } \
  if ((K) < 8) { LD(ap[(K)&7], abp + (size_t)((K)+8)*65536); }

#define RUN16X(LD) \
  LD(ap[0], abp);          LD(ap[1], abp+65536); \
  LD(ap[2], abp+131072);   LD(ap[3], abp+196608); \
  LD(ap[4], abp+262144);   LD(ap[5], abp+327680); \
  LD(ap[6], abp+393216);   LD(ap[7], abp+458752); \
  KSX( 0,7,LD) KSX( 1,7,LD) KSX( 2,7,LD) KSX( 3,7,LD) \
  KSX( 4,7,LD) KSX( 5,7,LD) KSX( 6,7,LD) KSX( 7,7,LD) \
  KSX( 8,7,LD) KSX( 9,6,LD) KSX(10,5,LD) KSX(11,4,LD) \
  KSX(12,3,LD) KSX(13,2,LD) KSX(14,1,LD) KSX(15,0,LD)

// ---- rotated pipeline (phase 1): chunk order starts at rot=ns; ap[0] was
// pre-issued (chunk rot) between gbar_arrive and gbar_wait.
#define C16(K) (((K) + rot) & 15)
#define KSXR(K, W, LD) \
  VWAIT(W); \
  { short8 a_  = *(short8*)&ap[(K)&7]; \
    short8 b0_ = *(const short8*)(wbp + (size_t)C16(K)*4096); \
    short8 b1_ = *(const short8*)(wbp + (size_t)C16(K)*4096 + 1024); \
    p0 = __builtin_amdgcn_mfma_f32_16x16x32_bf16(a_, b0_, p0, 0,0,0); \
    p1 = __builtin_amdgcn_mfma_f32_16x16x32_bf16(a_, b1_, p1, 0,0,0); } \
  if ((K) < 8) { LD(ap[(K)&7], abp + (size_t)C16((K)+8)*65536); }

#define RUN16R(LD) \
  LD(ap[1], abp + (size_t)C16(1)*65536); \
  LD(ap[2], abp + (size_t)C16(2)*65536); \
  LD(ap[3], abp + (size_t)C16(3)*65536); \
  LD(ap[4], abp + (size_t)C16(4)*65536); \
  LD(ap[5], abp + (size_t)C16(5)*65536); \
  LD(ap[6], abp + (size_t)C16(6)*65536); \
  LD(ap[7], abp + (size_t)C16(7)*65536); \
  KSXR( 0,7,LD) KSXR( 1,7,LD) KSXR( 2,7,LD) KSXR( 3,7,LD) \
  KSXR( 4,7,LD) KSXR( 5,7,LD) KSXR( 6,7,LD) KSXR( 7,7,LD) \
  KSXR( 8,7,LD) KSXR( 9,6,LD) KSXR(10,5,LD) KSXR(11,4,LD) \
  KSXR(12,3,LD) KSXR(13,2,LD) KSXR(14,1,LD) KSXR(15,0,LD)

// ---------------- persistent group-synced scan v9 ----------------
// R9-proven protocol + (a) XOR bank-swizzle on W1s/W2s (both sides),
// (b) phase-1 chunk rotation + own-chunk pre-issue under the barrier poll.
template<int UNIQ>
__global__ __launch_bounds__(512, 1) void k_scan(
    const float* __restrict__ coeffs, const float* __restrict__ times,
    const float* __restrict__ dW,     const float* __restrict__ W_init,
    const float* __restrict__ b_init,
    const unsigned short* __restrict__ W1T, const unsigned short* __restrict__ W2T,
    const float* __restrict__ bf1, const float* __restrict__ bg1,
    const float* __restrict__ bf2, const float* __restrict__ bg2,
    unsigned short* __restrict__ ygk, unsigned short* __restrict__ uk,
    float* __restrict__ z, unsigned* __restrict__ cnts){
  __shared__ __align__(16) unsigned char W1s[65536];   // [16 kc][64 col][4 fq] x16B, XOR-swizzled
  __shared__ __align__(16) unsigned char W2s[65536];   // col<32 f-slice, col>=32 g-slice
  __shared__ __align__(16) float cmb[64*68];           // x0 stage / f-result exchange
  __shared__ float tms[104];

  constexpr size_t YB = UNIQ ? (size_t)Bsz * H  * 2 : 0;   // 1 MB per step
  constexpr size_t UB = UNIQ ? (size_t)Bsz * H2 * 2 : 0;   // 2 MB per step

  const int bid = blockIdx.x, mt = bid & 15, ns = bid >> 4;
  const int m0 = mt*64, n1 = ns*64, n2 = ns*32;
  const int tid = threadIdx.x, lane = tid & 63, w = tid >> 6;
  const int fr = lane & 15, fq = lane >> 4;
  const int band = w & 3, isg = w >> 2;
  const int rot = ns;                        // phase-1 chunk rotation (own y chunk first)
  unsigned* cnt = cnts + mt*32;
  unsigned ep = 0;

  // ---- stage weight slices into LDS (frag-major, XOR bank swizzle) ----
  // addr = kc*4096 + ((cl*64 + fqi*16) ^ ((cl&7)<<4)); bijective within each kc.
  #pragma unroll
  for (int i = 0; i < 8; i++){
    int u = i*512 + tid;                     // unit = (kc*64+cl)*4+fqi
    int fqi = u & 3, cl = (u >> 2) & 63, kc = u >> 8;
    size_t dstoff = (size_t)kc*4096 + (size_t)((cl*64 + fqi*16) ^ ((cl & 7) << 4));
    *(uint4*)(W1s + dstoff) = *(const uint4*)(W1T + (size_t)(n1+cl)*512 + kc*32 + fqi*8);
    const unsigned short* s2 = (cl < 32) ? (W2T + (size_t)(n2+cl)*512)
                                         : (W2T + (size_t)262144 + (size_t)(n2+cl-32)*512);
    *(uint4*)(W2s + dstoff) = *(const uint4*)(s2 + kc*32 + fqi*8);
  }
  if (tid < 100) tms[tid] = times[tid];
  { int row = tid >> 3, c0 = (tid & 7)*8;
    const float* src = coeffs + (size_t)(m0+row)*(TM1*4*64) + c0;
    *(float4*)(&cmb[row*68 + c0])     = *(const float4*)src;
    *(float4*)(&cmb[row*68 + c0 + 4]) = *(const float4*)(src + 4);
  }
  __syncthreads();

  // per-lane pointers (base of step-0 buffers)
  char* ygkb = (char*)ygk;
  char* ukb  = (char*)uk;
  const char* ab1 = ygkb + ((size_t)(m0 + band*16 + fr))*64 + fq*16;
  const char* ab2 = ukb + (size_t)isg*1048576 + ((size_t)(m0 + band*16 + fr))*64 + fq*16;
  char* up = ukb  + (size_t)(ns*2 + isg)*65536 + ((size_t)(m0 + band*16 + fq*4))*64 + fr*4;
  char* yp = ygkb + (size_t)ns*65536           + ((size_t)(m0 + band*16 + fq*4))*64 + fr*4;
  // swizzled B-frag bases: col = isg*32 + fr (and +16 via +1024, mask-invariant)
  const unsigned char* wbp1 = W1s + isg*2048 + (size_t)((fr*64 + fq*16) ^ ((fr & 7) << 4));
  const unsigned char* wbp2 = W2s + isg*2048 + (size_t)((fr*64 + fq*16) ^ ((fr & 7) << 4));
  float* zp = z + ((size_t)(m0 + band*16 + fq*4))*T*512 + n2 + fr;

  // biases
  const float* b1src = (ns < 8) ? bf1 : bg1;
  const int    b1off = n1 - ((ns < 8) ? 0 : 512) + isg*32 + fr;
  const float b1v0 = b1src[b1off], b1v1 = b1src[b1off + 16];
  const float* b2src = isg ? bg2 : bf2;
  const float b2v0 = b2src[n2 + fr], b2v1 = b2src[n2 + 16 + fr];

  u32x4 ap[8];                               // A-prefetch ring (shared by both phases)

  // ---- init: y0 = x0 @ W_init + b_init (g-waves own y slice) -> y buffer 0 ----
  float yv[2][4];
  if (isg){
    #pragma unroll
    for (int r = 0; r < 4; r++){
      int lrow = band*16 + fq*4 + r;
      float s0 = b_init[n2 + fr], s1 = b_init[n2 + 16 + fr];
      #pragma unroll 8
      for (int k = 0; k < 64; k++){
        float xv = cmb[lrow*68 + k];
        s0 += xv * W_init[(size_t)k*512 + n2 + fr];
        s1 += xv * W_init[(size_t)k*512 + n2 + 16 + fr];
      }
      yv[0][r] = s0; yv[1][r] = s1;
      SC_STORE(yp + r*64, pack2(s0, s1));
      zp[(size_t)r*T*512]      = s0;
      zp[(size_t)r*T*512 + 16] = s1;
    }
    VWAIT(8);                                // 4 y-sc complete; z may linger
  }
  ++ep; gbar_arrive(cnt);
  // pre-issue own y(0) chunk (written+drained by this block's g-waves above)
  if constexpr (UNIQ) { AISSUE_L2(ap[0], ab1 + (size_t)rot*65536); }
  else                { AISSUE_CC(ap[0], ab1 + (size_t)rot*65536); }
  gbar_wait(cnt, ep*16);

  for (int t = 0; t < TM1; t++){
    float dv[8];
    // ===== phase 1: u(t) = tanh(y(t) @ W1 + b1), chunks rotated by ns =====
    {
      f32x4 p0 = {0.f,0.f,0.f,0.f}, p1 = {0.f,0.f,0.f,0.f};
      const char* abp = ab1 + (size_t)t*YB;
      const unsigned char* wbp = wbp1;
      if constexpr (UNIQ) { RUN16R(AISSUE_L2); } else { RUN16R(AISSUE_CC); }
      char* upt = up + (size_t)t*UB;
      #pragma unroll
      for (int r = 0; r < 4; r++)
        SC_STORE(upt + r*64, pack2(tanh_fast(p0[r] + b1v0), tanh_fast(p1[r] + b1v1)));
      if (isg){
        const char* dp = (const char*)dW + (((size_t)t*1024 + m0 + band*16 + fq*4)*512 + n2 + fr)*4;
        PLOAD(dv[0], dp + 0);      PLOAD(dv[1], dp + 64);
        PLOAD(dv[2], dp + 2048);   PLOAD(dv[3], dp + 2048+64);
        PLOAD(dv[4], dp + 4096);   PLOAD(dv[5], dp + 4096+64);
        PLOAD(dv[6], dp + 6144);   PLOAD(dv[7], dp + 6144+64);
        VWAIT(8);                            // 4 u-sc complete; dW in flight
      } else {
        VWAIT(0);
      }
    }
    ++ep; gbar_arrive(cnt); gbar_wait(cnt, ep*16);

    // ===== phase 2: f-waves u_f@Wf2 -> cmb; g-waves u_g@Wg2 + y update =====
    {
      f32x4 p0 = {0.f,0.f,0.f,0.f}, p1 = {0.f,0.f,0.f,0.f};
      const char* abp = ab2 + (size_t)t*UB;
      const unsigned char* wbp = wbp2;
      if constexpr (UNIQ) { RUN16X(AISSUE_L2); } else { RUN16X(AISSUE_CC); }
      if (!isg){
        #pragma unroll
        for (int r = 0; r < 4; r++){
          int lrow = band*16 + fq*4 + r;
          cmb[lrow*68 + fr]      = p0[r] + b2v0;
          cmb[lrow*68 + 16 + fr] = p1[r] + b2v1;
        }
      }
      __syncthreads();
      if (isg){
        float h  = tms[t+1] - tms[t];
        float sq = sqrtf(h);
        char* ypt = yp + (size_t)(t+1)*YB;
        #pragma unroll
        for (int r = 0; r < 4; r++){
          int lrow = band*16 + fq*4 + r;
          float f0 = cmb[lrow*68 + fr],       f1 = cmb[lrow*68 + 16 + fr];
          float g0 = tanh_fast(p0[r] + b2v0), g1 = tanh_fast(p1[r] + b2v1);
          float y0n = yv[0][r] + f0*h + g0*(sq*dv[r*2]);
          float y1n = yv[1][r] + f1*h + g1*(sq*dv[r*2+1]);
          yv[0][r] = y0n; yv[1][r] = y1n;
          SC_STORE(ypt + r*64, pack2(y0n, y1n));
          zp[(size_t)r*T*512 + (size_t)(t+1)*512]      = y0n;
          zp[(size_t)r*T*512 + (size_t)(t+1)*512 + 16] = y1n;
        }
        VWAIT(8);                            // 4 y-sc complete; z may linger
      }
    }
    if (t < TM1-1){
      ++ep; gbar_arrive(cnt);
      // pre-issue own y(t+1) chunk under the barrier poll
      { const char* pib = ab1 + (size_t)(t+1)*YB;
        if constexpr (UNIQ) { AISSUE_L2(ap[0], pib + (size_t)rot*65536); }
        else                { AISSUE_CC(ap[0], pib + (size_t)rot*65536); }
      }
      gbar_wait(cnt, ep*16);
    }
  }
}

// ---------------- fused readout (identical to R9) ----------------
__global__ __launch_bounds__(512, 1) void k_read(
    const float* __restrict__ z, const unsigned short* __restrict__ Wl1F,
    const float* __restrict__ bl1, const unsigned short* __restrict__ Wl2F,
    const float* __restrict__ bl2, float* __restrict__ out){
  __shared__ __align__(16) unsigned char zt[65536];
  __shared__ __align__(16) unsigned char relF[65536];
  const int tid = threadIdx.x, lane = tid & 63, w = tid >> 6;
  const int fr = lane & 15, fq = lane >> 4;
  const size_t rr0 = (size_t)blockIdx.x * 64;
  const int cw = w * 64;

  { int row = tid >> 3, c0 = (tid & 7) * 64;
    const float* zr = z + (rr0 + row) * 512 + c0;
    #pragma unroll
    for (int j = 0; j < 2; ++j){
      int kc = (c0 >> 5) + j;
      #pragma unroll
      for (int f = 0; f < 4; ++f){
        float4 v0 = *(const float4*)(zr + j*32 + f*8);
        float4 v1 = *(const float4*)(zr + j*32 + f*8 + 4);
        unsigned d0 = pack2(tanh_fast(v0.x), tanh_fast(v0.y));
        unsigned d1 = pack2(tanh_fast(v0.z), tanh_fast(v0.w));
        unsigned d2 = pack2(tanh_fast(v1.x), tanh_fast(v1.y));
        unsigned d3 = pack2(tanh_fast(v1.z), tanh_fast(v1.w));
        uint4 pk = {d0, d1, d2, d3};
        *(uint4*)(zt + (size_t)((kc*64 + row)*4 + f)*16) = pk;
      }
    }
  }
  __syncthreads();

  f32x4 acc[4][4];
  #pragma unroll
  for (int m = 0; m < 4; m++)
    #pragma unroll
    for (int c = 0; c < 4; c++) acc[m][c] = (f32x4){0.f,0.f,0.f,0.f};
  for (int kc = 0; kc < 16; ++kc){
    short8 a[4];
    #pragma unroll
    for (int m = 0; m < 4; m++)
      a[m] = *(const short8*)(zt + (size_t)((kc*64 + m*16 + fr)*4 + fq)*16);
    #pragma unroll
    for (int c = 0; c < 4; c++){
      short8 b = *(const short8*)(Wl1F + (((size_t)kc*512 + cw + c*16 + fr)*4 + fq)*8);
      #pragma unroll
      for (int m = 0; m < 4; m++)
        acc[m][c] = __builtin_amdgcn_mfma_f32_16x16x32_bf16(a[m], b, acc[m][c], 0, 0, 0);
    }
  }
  float bl1v[4];
  #pragma unroll
  for (int c = 0; c < 4; c++) bl1v[c] = bl1[cw + c*16 + fr];

  #pragma unroll
  for (int h = 0; h < 2; ++h){
    __syncthreads();
    if ((w >> 2) == h){
      float* stg = (float*)zt;
      int cb = cw - h*256;
      #pragma unroll
      for (int m = 0; m < 4; m++)
        #pragma unroll
        for (int c = 0; c < 4; c++)
          #pragma unroll
          for (int r = 0; r < 4; r++)
            stg[(m*16 + fq*4 + r)*256 + cb + c*16 + fr] = fmaxf(acc[m][c][r] + bl1v[c], 0.f);
    }
    __syncthreads();
    { int row = tid >> 3, c8 = (tid & 7) * 32;
      const float* stg = (const float*)zt;
      int kc = h*8 + (tid & 7);
      #pragma unroll
      for (int f = 0; f < 4; ++f){
        const float* p = stg + row*256 + c8 + f*8;
        unsigned d0 = pack2(p[0], p[1]);
        unsigned d1 = pack2(p[2], p[3]);
        unsigned d2 = pack2(p[4], p[5]);
        unsigned d3 = pack2(p[6], p[7]);
        uint4 pk = {d0, d1, d2, d3};
        *(uint4*)(relF + (size_t)((kc*64 + row)*4 + f)*16) = pk;
      }
    }
  }
  __syncthreads();

  f32x4 acc2[2];
  acc2[0] = (f32x4){0.f,0.f,0.f,0.f};
  acc2[1] = (f32x4){0.f,0.f,0.f,0.f};
  const int mt2 = w & 3, ocb = (w >> 2) * 32;
  for (int kc = 0; kc < 16; ++kc){
    short8 a = *(const short8*)(relF + (size_t)((kc*64 + mt2*16 + fr)*4 + fq)*16);
    #pragma unroll
    for (int j = 0; j < 2; j++){
      short8 b = *(const short8*)(Wl2F + (((size_t)(kc*64 + ocb + j*16 + fr))*4 + fq)*8);
      acc2[j] = __builtin_amdgcn_mfma_f32_16x16x32_bf16(a, b, acc2[j], 0, 0, 0);
    }
  }
  #pragma unroll
  for (int j = 0; j < 2; j++){
    #pragma unroll
    for (int r = 0; r < 4; r++){
      int row = mt2*16 + fq*4 + r;
      int oc  = ocb + j*16 + fr;
      out[(rr0 + row)*64 + oc] = acc2[j][r] + bl2[oc];
    }
  }
}

extern "C" void kernel_launch(void* const* d_in, const int* in_sizes, int n_in,
                              void* d_out, int out_size, void* d_ws, size_t ws_size,
                              hipStream_t stream){
  (void)in_sizes; (void)n_in; (void)out_size;
  const float* coeffs = (const float*)d_in[0];
  const float* times  = (const float*)d_in[1];
  const float* dW     = (const float*)d_in[2];
  const float* W_init = (const float*)d_in[3];
  const float* b_init = (const float*)d_in[4];
  const float* Wf1 = (const float*)d_in[5];
  const float* bf1 = (const float*)d_in[6];
  const float* Wf2 = (const float*)d_in[7];
  const float* bf2 = (const float*)d_in[8];
  const float* Wg1 = (const float*)d_in[9];
  const float* bg1 = (const float*)d_in[10];
  const float* Wg2 = (const float*)d_in[11];
  const float* bg2 = (const float*)d_in[12];
  const float* Wl1 = (const float*)d_in[13];
  const float* bl1 = (const float*)d_in[14];
  const float* Wl2 = (const float*)d_in[15];
  const float* bl2 = (const float*)d_in[16];

  float* out = (float*)d_out;
  float* z   = out + (size_t)Bsz * T * OUTD;   // z region of d_out, (B,T,H)

  // step-unique layout needs ~302 MB of workspace
  const bool full = ws_size >= ((size_t)320 << 20);

  char* wsp = (char*)d_ws;
  auto carve = [&](size_t bytes) -> void* {
    void* p = (void*)wsp; wsp += (bytes + 255) & ~(size_t)255; return p;
  };
  unsigned short* W1T  = (unsigned short*)carve((size_t)H2 * H * 2);
  unsigned short* W2T  = (unsigned short*)carve((size_t)H2 * H * 2);
  unsigned short* Wl1F = (unsigned short*)carve((size_t)H * H * 2);
  unsigned short* Wl2F = (unsigned short*)carve((size_t)OUTD * H * 2);
  unsigned short* ygk  = (unsigned short*)carve(full ? (size_t)T   * Bsz * H  * 2
                                                     : (size_t)Bsz * H  * 2);
  unsigned short* uk   = (unsigned short*)carve(full ? (size_t)TM1 * Bsz * H2 * 2
                                                     : (size_t)Bsz * H2 * 2);
  unsigned*       cnts = (unsigned*)carve(1024 * sizeof(unsigned));

  k_zero<<<dim3(4), 256, 0, stream>>>(cnts);
  k_prep<<<dim3(16, 16, 6), dim3(32, 8), 0, stream>>>(Wf1, Wg1, Wf2, Wg2, Wl1, Wl2,
                                                      W1T, W2T, Wl1F, Wl2F);
  if (full)
    k_scan<1><<<dim3(256), 512, 0, stream>>>(coeffs, times, dW, W_init, b_init,
                                             W1T, W2T, bf1, bg1, bf2, bg2,
                                             ygk, uk, z, cnts);
  else
    k_scan<0><<<dim3(256), 512, 0, stream>>>(coeffs, times, dW, W_init, b_init,
                                             W1T, W2T, bf1, bg1, bf2, bg2,
                                             ygk, uk, z, cnts);
  k_read<<<dim3(BT / 64), 512, 0, stream>>>(z, Wl1F, bl1, Wl2F, bl2, out);
}